// Round 14
// baseline (273.667 us; speedup 1.0000x reference)
//
#include <hip/hip_runtime.h>
#include <hip/hip_bf16.h>

#define NN 100000   // nodes
#define NE 1000000  // edges
#define EF 64       // edge features
#define IC 128      // in channels
#define OC 256      // out channels
#define CAP 48      // per-node edge capacity (max observed deg ~28, Poisson(10))

typedef __attribute__((ext_vector_type(8))) short bf16x8;
typedef __attribute__((ext_vector_type(4))) float f32x4;

static __device__ __forceinline__ ushort f2bf(float f) {
  unsigned u = __float_as_uint(f);
  u += 0x7fffu + ((u >> 16) & 1u);   // RNE (inputs have no NaN)
  return (ushort)(u >> 16);
}

// ---- 0. W prep (f32 [192][256] -> bf16 fragment-major) + zero cnt ----
__global__ __launch_bounds__(256) void wprep_kernel(
    const float* __restrict__ W, ushort* __restrict__ wfrag,
    int* __restrict__ cnt) {
  int t = blockIdx.x * 256 + threadIdx.x;  // 0..49151
  int i = t & 7;
  int lane = (t >> 3) & 63;
  int ct = (t >> 9) & 15;
  int s = t >> 13;  // 0..5
  int k = s * 32 + (lane >> 4) * 8 + i;
  int col = ct * 16 + (lane & 15);
  wfrag[t] = f2bf(W[(size_t)k * OC + col]);
  for (int j = t; j < NN; j += 192 * 256) cnt[j] = 0;
}

// ---- 1. bucket-scatter packed (eid, weight) into fixed strips ----
__global__ __launch_bounds__(256) void place_kernel(const int4* __restrict__ tgt4,
                                                    const float4* __restrict__ ew4,
                                                    int* __restrict__ cnt,
                                                    int2* __restrict__ epack) {
  int q = blockIdx.x * 256 + threadIdx.x;
  if (q < NE / 4) {
    int4 t = tgt4[q];
    float4 w = ew4[q];
    int e = q * 4;
    int p;
    p = atomicAdd(&cnt[t.x], 1);
    if (p < CAP) epack[(size_t)t.x * CAP + p] = make_int2(e,     __float_as_int(w.x));
    p = atomicAdd(&cnt[t.y], 1);
    if (p < CAP) epack[(size_t)t.y * CAP + p] = make_int2(e + 1, __float_as_int(w.y));
    p = atomicAdd(&cnt[t.z], 1);
    if (p < CAP) epack[(size_t)t.z * CAP + p] = make_int2(e + 2, __float_as_int(w.z));
    p = atomicAdd(&cnt[t.w], 1);
    if (p < CAP) epack[(size_t)t.w * CAP + p] = make_int2(e + 3, __float_as_int(w.w));
  }
}

// ---- 2. FUSED gather-aggregate + concat-GEMM + bias + relu ----
// Block = 64 output rows. Phase 1: each wave aggregates its 16 nodes into
// LDS mean_s (wave-private rows). Phase 2: R13 MFMA + LDS-transposed epilogue.
// Mixing gather blocks with MFMA/streaming blocks fills DRAM slots that a
// pure random-gather kernel leaves idle.
__global__ __launch_bounds__(256) void fused_kernel(
    const int* __restrict__ cnt, const int2* __restrict__ epack,
    const float* __restrict__ ea, const float* __restrict__ nwt,
    const float* __restrict__ na, const ushort* __restrict__ wfrag,
    const float* __restrict__ bias, float* __restrict__ out) {
  __shared__ ushort mean_s[64][72];  // 72-ush row stride = 144 B (16-B aligned)
  __shared__ float cs[4][16][130];   // epilogue slab (+2 pad cols)

  int tid = threadIdx.x;
  int lane = tid & 63;
  int wv = tid >> 6;
  int ns = lane >> 4;   // node slot 0..3
  int fq = lane & 15;   // feature quad
  int row_base = blockIdx.x * 64;

  // ---- phase 1: aggregate this wave's 16 nodes (4 per k-iteration) ----
  for (int k = 0; k < 4; ++k) {
    int n_local = wv * 16 + k * 4 + ns;
    int n = row_base + n_local;
    int nsafe = min(n, NN - 1);
    int deg = (n < NN) ? cnt[nsafe] : 0;
    int dclamp = max(deg - 1, 0);
    const int2* strip = epack + (size_t)nsafe * CAP;

    int md = deg;
    md = max(md, __shfl_xor(md, 16, 64));
    md = max(md, __shfl_xor(md, 32, 64));

    f32x4 acc = (f32x4)(0.0f);
    for (int j = 0; j < md; j += 8) {
#pragma unroll
      for (int u = 0; u < 8; ++u) {
        int jj = j + u;
        int c = min(jj, dclamp);
        int2 m = strip[c];
        float w = (jj < deg) ? __int_as_float(m.y) : 0.0f;
        int e = (deg > 0) ? m.x : 0;
        f32x4 v = *(const f32x4*)(ea + (size_t)e * EF + fq * 4);
        acc += v * w;
      }
    }

    float scale = (n < NN) ? nwt[nsafe] / (float)max(deg, 1) : 0.0f;
    ushort4 o;
    o.x = f2bf(acc[0] * scale);
    o.y = f2bf(acc[1] * scale);
    o.z = f2bf(acc[2] * scale);
    o.w = f2bf(acc[3] * scale);
    *(ushort4*)&mean_s[n_local][fq * 4] = o;
  }
  __syncthreads();

  // ---- phase 2: GEMM over rows [row_base, row_base+64) ----
  int wrow = wv * 16;               // this wave's 16 rows
  int r = row_base + wrow + (lane & 15);
  int rc = min(r, NN - 1);          // clamp tail; stores are guarded
  int kofs = (lane >> 4) * 8;       // element offset within a K=32 step
  int colb = lane & 15;
  int rgrp = lane >> 4;

  const float* narow = na + (size_t)rc * IC;
  const ushort* mrow = &mean_s[wrow + (lane & 15)][0];

  bf16x8 afrag[6];
#pragma unroll
  for (int s = 0; s < 4; ++s) {
    f32x4 lo = *(const f32x4*)(narow + s * 32 + kofs);
    f32x4 hi = *(const f32x4*)(narow + s * 32 + kofs + 4);
#pragma unroll
    for (int i = 0; i < 4; ++i) {
      afrag[s][i] = (short)f2bf(lo[i]);
      afrag[s][4 + i] = (short)f2bf(hi[i]);
    }
  }
#pragma unroll
  for (int s = 0; s < 2; ++s)
    afrag[4 + s] = *(const bf16x8*)(mrow + s * 32 + kofs);

  f32x4 acc[16];
#pragma unroll
  for (int ct = 0; ct < 16; ++ct) acc[ct] = (f32x4)(0.0f);

#pragma unroll
  for (int s = 0; s < 6; ++s) {
#pragma unroll
    for (int ct = 0; ct < 16; ++ct) {
      bf16x8 bfrag =
          *(const bf16x8*)(wfrag + ((size_t)((s * 16 + ct) * 64 + lane) * 8));
      acc[ct] =
          __builtin_amdgcn_mfma_f32_16x16x32_bf16(afrag[s], bfrag, acc[ct], 0, 0, 0);
    }
  }

  // C/D layout (m89-verified): acc[ct][i] = (row rgrp*4+i, col ct*16+colb)
#pragma unroll
  for (int h = 0; h < 2; ++h) {
#pragma unroll
    for (int t = 0; t < 8; ++t) {
      int ct = h * 8 + t;
      float bv = bias[ct * 16 + colb];
#pragma unroll
      for (int i = 0; i < 4; ++i)
        cs[wv][rgrp * 4 + i][t * 16 + colb] = fmaxf(acc[ct][i] + bv, 0.0f);
    }
    __syncthreads();
#pragma unroll
    for (int k = 0; k < 8; ++k) {
      int row = 2 * k + (lane >> 5);
      int c4 = (lane & 31) * 4;
      f32x4 v = *(const f32x4*)&cs[wv][row][c4];
      int gr = row_base + wrow + row;
      if (gr < NN)
        __builtin_nontemporal_store(v, (f32x4*)(out + (size_t)gr * OC + h * 128 + c4));
    }
    __syncthreads();
  }
}

extern "C" void kernel_launch(void* const* d_in, const int* in_sizes, int n_in,
                              void* d_out, int out_size, void* d_ws, size_t ws_size,
                              hipStream_t stream) {
  const int* edge_index = (const int*)d_in[0];    // [2][NE], row 0 = targets
  const float* edge_attr = (const float*)d_in[1]; // [NE][EF]
  const float* node_attr = (const float*)d_in[2]; // [NN][IC]
  const float* edge_weight = (const float*)d_in[3];
  const float* node_weight = (const float*)d_in[4];
  const float* W = (const float*)d_in[5];         // [192][256]
  const float* bias = (const float*)d_in[6];
  float* out = (float*)d_out;

  char* p = (char*)d_ws;
  int2* epack    = (int2*)p;                       // NN*CAP*8 = 38,400,000 B
  int* cnt       = (int*)(p + 38400000);           // 400,000 B
  ushort* wfrag  = (ushort*)(p + 38800000);        // 98,304 B (16B-aligned)

  wprep_kernel<<<192, 256, 0, stream>>>(W, wfrag, cnt);
  place_kernel<<<(NE / 4 + 255) / 256, 256, 0, stream>>>(
      (const int4*)edge_index, (const float4*)edge_weight, cnt, epack);
  fused_kernel<<<(NN + 63) / 64, 256, 0, stream>>>(
      cnt, epack, edge_attr, node_weight, node_attr, wfrag, bias, out);
}

// Round 15
// 238.866 us; speedup vs baseline: 1.1457x; 1.1457x over previous
//
#include <hip/hip_runtime.h>
#include <hip/hip_bf16.h>

#define NN 100000   // nodes
#define NE 1000000  // edges
#define EF 64       // edge features
#define IC 128      // in channels
#define OC 256      // out channels
#define CAP 48      // per-node edge capacity (max observed deg ~28, Poisson(10))

typedef __attribute__((ext_vector_type(8))) short bf16x8;
typedef __attribute__((ext_vector_type(4))) float f32x4;

static __device__ __forceinline__ ushort f2bf(float f) {
  unsigned u = __float_as_uint(f);
  u += 0x7fffu + ((u >> 16) & 1u);   // RNE (inputs have no NaN)
  return (ushort)(u >> 16);
}

// ---- 0. W prep (f32 [192][256] -> bf16 fragment-major) + zero cnt ----
__global__ __launch_bounds__(256) void wprep_kernel(
    const float* __restrict__ W, ushort* __restrict__ wfrag,
    int* __restrict__ cnt) {
  int t = blockIdx.x * 256 + threadIdx.x;  // 0..49151
  int i = t & 7;
  int lane = (t >> 3) & 63;
  int ct = (t >> 9) & 15;
  int s = t >> 13;  // 0..5
  int k = s * 32 + (lane >> 4) * 8 + i;
  int col = ct * 16 + (lane & 15);
  wfrag[t] = f2bf(W[(size_t)k * OC + col]);
  for (int j = t; j < NN; j += 192 * 256) cnt[j] = 0;
}

// ---- 1. bucket-scatter packed (eid, weight) into fixed strips ----
__global__ __launch_bounds__(256) void place_kernel(const int4* __restrict__ tgt4,
                                                    const float4* __restrict__ ew4,
                                                    int* __restrict__ cnt,
                                                    int2* __restrict__ epack) {
  int q = blockIdx.x * 256 + threadIdx.x;
  if (q < NE / 4) {
    int4 t = tgt4[q];
    float4 w = ew4[q];
    int e = q * 4;
    int p;
    p = atomicAdd(&cnt[t.x], 1);
    if (p < CAP) epack[(size_t)t.x * CAP + p] = make_int2(e,     __float_as_int(w.x));
    p = atomicAdd(&cnt[t.y], 1);
    if (p < CAP) epack[(size_t)t.y * CAP + p] = make_int2(e + 1, __float_as_int(w.y));
    p = atomicAdd(&cnt[t.z], 1);
    if (p < CAP) epack[(size_t)t.z * CAP + p] = make_int2(e + 2, __float_as_int(w.z));
    p = atomicAdd(&cnt[t.w], 1);
    if (p < CAP) epack[(size_t)t.w * CAP + p] = make_int2(e + 3, __float_as_int(w.w));
  }
}

// ---- 2. gather-aggregate: 4 nodes per wave; 16-deep unroll ----
// md (= wave-max degree) ~16, so one unrolled batch covers the whole strip:
// one strip-load front, then 16 independent ea gathers in flight per lane.
__global__ __launch_bounds__(256) void agg_kernel(
    const int* __restrict__ cnt, const int2* __restrict__ epack,
    const float* __restrict__ ea, const float* __restrict__ nwt,
    ushort* __restrict__ mean_bf) {
  int lane = threadIdx.x & 63;
  int wv = threadIdx.x >> 6;
  int ns = lane >> 4;   // node slot 0..3
  int fq = lane & 15;   // feature quad -> floats 4*fq..4*fq+3
  int n = blockIdx.x * 16 + wv * 4 + ns;   // NN = 6250*16 exactly

  int deg = cnt[n];
  int dclamp = max(deg - 1, 0);
  const int2* strip = epack + (size_t)n * CAP;

  // wave-max degree (deg uniform within each 16-lane group)
  int md = deg;
  md = max(md, __shfl_xor(md, 16, 64));
  md = max(md, __shfl_xor(md, 32, 64));

  f32x4 acc = (f32x4)(0.0f);
  for (int j = 0; j < md; j += 16) {
#pragma unroll
    for (int u = 0; u < 16; ++u) {
      int jj = j + u;
      int c = min(jj, dclamp);
      int2 m = strip[c];
      float w = (jj < deg) ? __int_as_float(m.y) : 0.0f;
      int e = (deg > 0) ? m.x : 0;
      f32x4 v = *(const f32x4*)(ea + (size_t)e * EF + fq * 4);
      acc += v * w;
    }
  }

  float scale = nwt[n] / (float)max(deg, 1);
  ushort4 o;
  o.x = f2bf(acc[0] * scale);
  o.y = f2bf(acc[1] * scale);
  o.z = f2bf(acc[2] * scale);
  o.w = f2bf(acc[3] * scale);
  *(ushort4*)(mean_bf + (size_t)n * EF + fq * 4) = o;
}

// ---- 3. fused concat + GEMM + bias + relu; LDS-transposed epilogue ----
__global__ __launch_bounds__(256) void gemm_kernel(
    const float* __restrict__ na, const ushort* __restrict__ mean_bf,
    const ushort* __restrict__ wfrag, const float* __restrict__ bias,
    float* __restrict__ out) {
  __shared__ float cs[4][16][130];   // per-wave slab; +2 pad cols (33,280 B)
  int tid = threadIdx.x;
  int lane = tid & 63;
  int wv = tid >> 6;
  int row_base = blockIdx.x * 64 + wv * 16;
  int r = row_base + (lane & 15);
  int rc = min(r, NN - 1);          // clamp tail; stores are guarded
  int kofs = (lane >> 4) * 8;       // element offset within a K=32 step
  int colb = lane & 15;
  int rgrp = lane >> 4;

  const float* narow = na + (size_t)rc * IC;
  const ushort* mrow = mean_bf + (size_t)rc * EF;

  bf16x8 afrag[6];
#pragma unroll
  for (int s = 0; s < 4; ++s) {
    f32x4 lo = *(const f32x4*)(narow + s * 32 + kofs);
    f32x4 hi = *(const f32x4*)(narow + s * 32 + kofs + 4);
#pragma unroll
    for (int i = 0; i < 4; ++i) {
      afrag[s][i] = (short)f2bf(lo[i]);
      afrag[s][4 + i] = (short)f2bf(hi[i]);
    }
  }
#pragma unroll
  for (int s = 0; s < 2; ++s)
    afrag[4 + s] = *(const bf16x8*)(mrow + s * 32 + kofs);

  f32x4 acc[16];
#pragma unroll
  for (int ct = 0; ct < 16; ++ct) acc[ct] = (f32x4)(0.0f);

#pragma unroll
  for (int s = 0; s < 6; ++s) {
#pragma unroll
    for (int ct = 0; ct < 16; ++ct) {
      bf16x8 bfrag =
          *(const bf16x8*)(wfrag + ((size_t)((s * 16 + ct) * 64 + lane) * 8));
      acc[ct] =
          __builtin_amdgcn_mfma_f32_16x16x32_bf16(afrag[s], bfrag, acc[ct], 0, 0, 0);
    }
  }

  // C/D layout (m89-verified): acc[ct][i] = (row rgrp*4+i, col ct*16+colb)
#pragma unroll
  for (int h = 0; h < 2; ++h) {
#pragma unroll
    for (int t = 0; t < 8; ++t) {
      int ct = h * 8 + t;
      float bv = bias[ct * 16 + colb];
#pragma unroll
      for (int i = 0; i < 4; ++i)
        cs[wv][rgrp * 4 + i][t * 16 + colb] = fmaxf(acc[ct][i] + bv, 0.0f);
    }
    __syncthreads();
#pragma unroll
    for (int k = 0; k < 8; ++k) {
      int row = 2 * k + (lane >> 5);
      int c4 = (lane & 31) * 4;
      f32x4 v = *(const f32x4*)&cs[wv][row][c4];
      int gr = row_base + row;
      if (gr < NN)
        __builtin_nontemporal_store(v, (f32x4*)(out + (size_t)gr * OC + h * 128 + c4));
    }
    __syncthreads();
  }
}

extern "C" void kernel_launch(void* const* d_in, const int* in_sizes, int n_in,
                              void* d_out, int out_size, void* d_ws, size_t ws_size,
                              hipStream_t stream) {
  const int* edge_index = (const int*)d_in[0];    // [2][NE], row 0 = targets
  const float* edge_attr = (const float*)d_in[1]; // [NE][EF]
  const float* node_attr = (const float*)d_in[2]; // [NN][IC]
  const float* edge_weight = (const float*)d_in[3];
  const float* node_weight = (const float*)d_in[4];
  const float* W = (const float*)d_in[5];         // [192][256]
  const float* bias = (const float*)d_in[6];
  float* out = (float*)d_out;

  char* p = (char*)d_ws;
  ushort* mean_bf = (ushort*)p;                    // 12,800,000 B
  int2* epack    = (int2*)(p + 12800000);          // NN*CAP*8 = 38,400,000 B
  int* cnt       = (int*)(p + 51200000);           // 400,000 B
  ushort* wfrag  = (ushort*)(p + 51600000);        // 98,304 B (16B-aligned)

  wprep_kernel<<<192, 256, 0, stream>>>(W, wfrag, cnt);
  place_kernel<<<(NE / 4 + 255) / 256, 256, 0, stream>>>(
      (const int4*)edge_index, (const float4*)edge_weight, cnt, epack);
  agg_kernel<<<NN / 16, 256, 0, stream>>>(cnt, epack, edge_attr,
                                          node_weight, mean_bf);
  gemm_kernel<<<(NN + 63) / 64, 256, 0, stream>>>(node_attr, mean_bf, wfrag,
                                                  bias, out);
}

// Round 16
// 202.159 us; speedup vs baseline: 1.3537x; 1.1816x over previous
//
#include <hip/hip_runtime.h>
#include <hip/hip_bf16.h>

#define NN 100000   // nodes
#define NE 1000000  // edges
#define EF 64       // edge features
#define IC 128      // in channels
#define OC 256      // out channels
#define CAP 48      // per-node edge capacity (max observed deg ~28, Poisson(10))

typedef __attribute__((ext_vector_type(8))) short bf16x8;
typedef __attribute__((ext_vector_type(4))) float f32x4;

static __device__ __forceinline__ ushort f2bf(float f) {
  unsigned u = __float_as_uint(f);
  u += 0x7fffu + ((u >> 16) & 1u);   // RNE (inputs have no NaN)
  return (ushort)(u >> 16);
}

// ---- 0. W prep (f32 [192][256] -> bf16 fragment-major) + zero cnt ----
__global__ __launch_bounds__(256) void wprep_kernel(
    const float* __restrict__ W, ushort* __restrict__ wfrag,
    int* __restrict__ cnt) {
  int t = blockIdx.x * 256 + threadIdx.x;  // 0..49151
  int i = t & 7;
  int lane = (t >> 3) & 63;
  int ct = (t >> 9) & 15;
  int s = t >> 13;  // 0..5
  int k = s * 32 + (lane >> 4) * 8 + i;
  int col = ct * 16 + (lane & 15);
  wfrag[t] = f2bf(W[(size_t)k * OC + col]);
  for (int j = t; j < NN; j += 192 * 256) cnt[j] = 0;
}

// ---- 1. bucket-scatter packed (eid, weight) into fixed strips ----
__global__ __launch_bounds__(256) void place_kernel(const int4* __restrict__ tgt4,
                                                    const float4* __restrict__ ew4,
                                                    int* __restrict__ cnt,
                                                    int2* __restrict__ epack) {
  int q = blockIdx.x * 256 + threadIdx.x;
  if (q < NE / 4) {
    int4 t = tgt4[q];
    float4 w = ew4[q];
    int e = q * 4;
    int p;
    p = atomicAdd(&cnt[t.x], 1);
    if (p < CAP) epack[(size_t)t.x * CAP + p] = make_int2(e,     __float_as_int(w.x));
    p = atomicAdd(&cnt[t.y], 1);
    if (p < CAP) epack[(size_t)t.y * CAP + p] = make_int2(e + 1, __float_as_int(w.y));
    p = atomicAdd(&cnt[t.z], 1);
    if (p < CAP) epack[(size_t)t.z * CAP + p] = make_int2(e + 2, __float_as_int(w.z));
    p = atomicAdd(&cnt[t.w], 1);
    if (p < CAP) epack[(size_t)t.w * CAP + p] = make_int2(e + 3, __float_as_int(w.w));
  }
}

// ---- 2. gather-aggregate: 4 nodes per wave; 8-deep unroll (measured best) ----
__global__ __launch_bounds__(256) void agg_kernel(
    const int* __restrict__ cnt, const int2* __restrict__ epack,
    const float* __restrict__ ea, const float* __restrict__ nwt,
    ushort* __restrict__ mean_bf) {
  int lane = threadIdx.x & 63;
  int wv = threadIdx.x >> 6;
  int ns = lane >> 4;   // node slot 0..3
  int fq = lane & 15;   // feature quad -> floats 4*fq..4*fq+3
  int n = blockIdx.x * 16 + wv * 4 + ns;   // NN = 6250*16 exactly

  int deg = cnt[n];
  int dclamp = max(deg - 1, 0);
  const int2* strip = epack + (size_t)n * CAP;

  // wave-max degree (deg uniform within each 16-lane group)
  int md = deg;
  md = max(md, __shfl_xor(md, 16, 64));
  md = max(md, __shfl_xor(md, 32, 64));

  f32x4 acc = (f32x4)(0.0f);
  for (int j = 0; j < md; j += 8) {
#pragma unroll
    for (int u = 0; u < 8; ++u) {
      int jj = j + u;
      int c = min(jj, dclamp);
      int2 m = strip[c];
      float w = (jj < deg) ? __int_as_float(m.y) : 0.0f;
      int e = (deg > 0) ? m.x : 0;
      f32x4 v = *(const f32x4*)(ea + (size_t)e * EF + fq * 4);
      acc += v * w;
    }
  }

  float scale = nwt[n] / (float)max(deg, 1);
  ushort4 o;
  o.x = f2bf(acc[0] * scale);
  o.y = f2bf(acc[1] * scale);
  o.z = f2bf(acc[2] * scale);
  o.w = f2bf(acc[3] * scale);
  *(ushort4*)(mean_bf + (size_t)n * EF + fq * 4) = o;
}

// ---- 3. fused concat + GEMM + bias + relu; LDS-transposed epilogue ----
__global__ __launch_bounds__(256) void gemm_kernel(
    const float* __restrict__ na, const ushort* __restrict__ mean_bf,
    const ushort* __restrict__ wfrag, const float* __restrict__ bias,
    float* __restrict__ out) {
  __shared__ float cs[4][16][130];   // per-wave slab; +2 pad cols (33,280 B)
  int tid = threadIdx.x;
  int lane = tid & 63;
  int wv = tid >> 6;
  int row_base = blockIdx.x * 64 + wv * 16;
  int r = row_base + (lane & 15);
  int rc = min(r, NN - 1);          // clamp tail; stores are guarded
  int kofs = (lane >> 4) * 8;       // element offset within a K=32 step
  int colb = lane & 15;
  int rgrp = lane >> 4;

  const float* narow = na + (size_t)rc * IC;
  const ushort* mrow = mean_bf + (size_t)rc * EF;

  bf16x8 afrag[6];
#pragma unroll
  for (int s = 0; s < 4; ++s) {
    f32x4 lo = *(const f32x4*)(narow + s * 32 + kofs);
    f32x4 hi = *(const f32x4*)(narow + s * 32 + kofs + 4);
#pragma unroll
    for (int i = 0; i < 4; ++i) {
      afrag[s][i] = (short)f2bf(lo[i]);
      afrag[s][4 + i] = (short)f2bf(hi[i]);
    }
  }
#pragma unroll
  for (int s = 0; s < 2; ++s)
    afrag[4 + s] = *(const bf16x8*)(mrow + s * 32 + kofs);

  f32x4 acc[16];
#pragma unroll
  for (int ct = 0; ct < 16; ++ct) acc[ct] = (f32x4)(0.0f);

#pragma unroll
  for (int s = 0; s < 6; ++s) {
#pragma unroll
    for (int ct = 0; ct < 16; ++ct) {
      bf16x8 bfrag =
          *(const bf16x8*)(wfrag + ((size_t)((s * 16 + ct) * 64 + lane) * 8));
      acc[ct] =
          __builtin_amdgcn_mfma_f32_16x16x32_bf16(afrag[s], bfrag, acc[ct], 0, 0, 0);
    }
  }

  // C/D layout (m89-verified): acc[ct][i] = (row rgrp*4+i, col ct*16+colb)
#pragma unroll
  for (int h = 0; h < 2; ++h) {
#pragma unroll
    for (int t = 0; t < 8; ++t) {
      int ct = h * 8 + t;
      float bv = bias[ct * 16 + colb];
#pragma unroll
      for (int i = 0; i < 4; ++i)
        cs[wv][rgrp * 4 + i][t * 16 + colb] = fmaxf(acc[ct][i] + bv, 0.0f);
    }
    __syncthreads();
#pragma unroll
    for (int k = 0; k < 8; ++k) {
      int row = 2 * k + (lane >> 5);
      int c4 = (lane & 31) * 4;
      f32x4 v = *(const f32x4*)&cs[wv][row][c4];
      int gr = row_base + row;
      if (gr < NN)
        __builtin_nontemporal_store(v, (f32x4*)(out + (size_t)gr * OC + h * 128 + c4));
    }
    __syncthreads();
  }
}

extern "C" void kernel_launch(void* const* d_in, const int* in_sizes, int n_in,
                              void* d_out, int out_size, void* d_ws, size_t ws_size,
                              hipStream_t stream) {
  const int* edge_index = (const int*)d_in[0];    // [2][NE], row 0 = targets
  const float* edge_attr = (const float*)d_in[1]; // [NE][EF]
  const float* node_attr = (const float*)d_in[2]; // [NN][IC]
  const float* edge_weight = (const float*)d_in[3];
  const float* node_weight = (const float*)d_in[4];
  const float* W = (const float*)d_in[5];         // [192][256]
  const float* bias = (const float*)d_in[6];
  float* out = (float*)d_out;

  char* p = (char*)d_ws;
  ushort* mean_bf = (ushort*)p;                    // 12,800,000 B
  int2* epack    = (int2*)(p + 12800000);          // NN*CAP*8 = 38,400,000 B
  int* cnt       = (int*)(p + 51200000);           // 400,000 B
  ushort* wfrag  = (ushort*)(p + 51600000);        // 98,304 B (16B-aligned)

  wprep_kernel<<<192, 256, 0, stream>>>(W, wfrag, cnt);
  place_kernel<<<(NE / 4 + 255) / 256, 256, 0, stream>>>(
      (const int4*)edge_index, (const float4*)edge_weight, cnt, epack);
  agg_kernel<<<NN / 16, 256, 0, stream>>>(cnt, epack, edge_attr,
                                          node_weight, mean_bf);
  gemm_kernel<<<(NN + 63) / 64, 256, 0, stream>>>(node_attr, mean_bf, wfrag,
                                                  bias, out);
}